// Round 2
// baseline (825.568 us; speedup 1.0000x reference)
//
#include <hip/hip_runtime.h>

// Problem constants (B=4, L=4096, D=1024 fixed by the reference setup)
#define B_ 4
#define L_ 4096
#define D_ 1024
#define M_ (B_*L_)              // 16384 rows
#define LC 64                   // scan chunk length
#define NC (L_/LC)              // 64 chunks
#define SLOT ((size_t)M_*D_)    // elements per output slot (16,777,216)

typedef __attribute__((ext_vector_type(4))) float f4;
typedef __bf16 bf16x8 __attribute__((ext_vector_type(8)));

__device__ __forceinline__ unsigned short f2bf(float f) {
  unsigned int u = __float_as_uint(f);
  u += 0x7FFFu + ((u >> 16) & 1u);         // round-to-nearest-even
  return (unsigned short)(u >> 16);
}
__device__ __forceinline__ float sigmoidf_(float x) { return 1.f / (1.f + __expf(-x)); }
__device__ __forceinline__ float siluf_(float x)    { return x / (1.f + __expf(-x)); }

#define GLL(src, dst) __builtin_amdgcn_global_load_lds( \
    (const __attribute__((address_space(1))) void*)(src), \
    (__attribute__((address_space(3))) void*)(dst), 16, 0, 0)

// ---------------- weight transpose + fp32->bf16 convert -------------------
// W [K=1024][N=1024] row-major fp32  ->  Wt [N][K] bf16 (B^T layout for GEMM)
__global__ __launch_bounds__(256) void transpose_cvt(
    const float* __restrict__ Wa, const float* __restrict__ Wb,
    const float* __restrict__ Wc,
    unsigned short* __restrict__ Wab, unsigned short* __restrict__ Wct) {
  __shared__ float tile[32][33];
  const float* src = (blockIdx.z == 0) ? Wa : (blockIdx.z == 1 ? Wb : Wc);
  unsigned short* dst = (blockIdx.z == 2) ? Wct
                        : (Wab + (blockIdx.z == 1 ? (size_t)D_*D_ : 0));
  int n = blockIdx.x*32 + threadIdx.x;     // source col
  int k0 = blockIdx.y*32;                  // source row base
  for (int i = threadIdx.y; i < 32; i += 8)
    tile[i][threadIdx.x] = src[(size_t)(k0+i)*D_ + n];
  __syncthreads();
  int k = k0 + threadIdx.x;
  int n0 = blockIdx.x*32;
  for (int i = threadIdx.y; i < 32; i += 8)
    dst[(size_t)(n0+i)*D_ + k] = f2bf(tile[threadIdx.x][i]);
}

// ---------------- RMSNorm -> bf16 ----------------------------------------
__global__ __launch_bounds__(256) void rmsnorm_bf16(
    const float* __restrict__ ctx, const float* __restrict__ g,
    unsigned short* __restrict__ out) {
  const size_t row = blockIdx.x;
  const int t = threadIdx.x;
  f4 xv = ((const f4*)(ctx + row*D_))[t];
  float ss = xv.x*xv.x + xv.y*xv.y + xv.z*xv.z + xv.w*xv.w;
  #pragma unroll
  for (int o = 32; o > 0; o >>= 1) ss += __shfl_down(ss, o);
  __shared__ float red[4];
  if ((t & 63) == 0) red[t >> 6] = ss;
  __syncthreads();
  float tot = red[0] + red[1] + red[2] + red[3];
  float sc = rsqrtf(tot * (1.f/(float)D_) + 1e-6f);
  f4 gv = ((const f4*)g)[t];
  f4 y = xv * sc * gv;
  ushort4 o4; o4.x = f2bf(y.x); o4.y = f2bf(y.y); o4.z = f2bf(y.z); o4.w = f2bf(y.w);
  ((ushort4*)out)[row*(D_/4) + t] = o4;
}

// ---------------- bf16 MFMA GEMM kernels ----------------------------------
// Both GEMMs use:
//  * double-buffered LDS 2-phase pipeline (T3 minimum recipe): issue next
//    tile's global_load_lds BEFORE ds_read+MFMA of current; ONE barrier/iter.
//  * conflict-free LDS layout: sub-tile (blk16 = row>>4) stored as
//    blk16*1024B + q*256B + r16*16B. global_load_lds writes base+lane*16
//    linearly, so the staging SOURCE is lane-permuted (row=lane&15,
//    k=(lane>>4)*8) to produce this layout; fragment reads are then
//    base + lane*16 -- dense in lane order, zero bank conflicts.
//    Global-side coalescing unchanged (16 x 64B segments either way).
#define BM 128
#define BN 128
#define BK 32

// Fused dual-weight GEMM: 128x64 tile of A@Wa^T AND A@Wb^T per block.
// Epilogue: alpha=sigmoid, beta=silu, x = v*beta*sqrt(clip(1-alpha^2)), v copy.
__global__ __launch_bounds__(256) void gemm_ab(
    const unsigned short* __restrict__ A, const unsigned short* __restrict__ Wab,
    const float* __restrict__ b_alpha, const float* __restrict__ b_beta,
    const float* __restrict__ v,
    float* __restrict__ alphas, float* __restrict__ x, float* __restrict__ v_out) {
  // per buffer (shorts): A [0,4096)  B [4096,8192)  (B0 blk 0..3, B1 blk 4..7)
  __shared__ unsigned short lds[2*8192];   // 32 KB double-buffered
  const int tid  = threadIdx.x;
  const int wave = tid >> 6;
  const int lane = tid & 63;
  const int q    = lane >> 4;              // k-quad 0..3 (fragment reads)
  const int l16  = lane & 15;
  const int wmblk = (wave >> 1) * 4;       // A blk16 base for this wave
  const int wnblk = (wave & 1) * 2;        // B blk16 base within each weight

  const int bx = blockIdx.x;               // 16 n-tiles of 64
  const int by = blockIdx.y;               // 128 m-tiles of 128

  // staging source (lane-permuted for the swizzled LDS layout):
  const int sr = lane & 15;                // row within 16-row sub-tile
  const int sk = (lane >> 4) * 8;          // k offset (shorts)
  const unsigned short* Ag = A + ((size_t)by*BM + wave*32 + sr) * D_ + sk;
  const unsigned short* Bg = Wab + ((size_t)(wave>>1)*D_ + (size_t)bx*64 + (wave&1)*32 + sr) * D_ + sk;

  f4 acc[4][2][2] = {};                    // [m-frag][n-frag][weight]

  // prologue: stage tile 0, drain, enter loop
  GLL(Ag,          lds + wave*1024);
  GLL(Ag + 16*D_,  lds + wave*1024 + 512);
  GLL(Bg,          lds + 4096 + wave*1024);
  GLL(Bg + 16*D_,  lds + 4096 + wave*1024 + 512);
  __syncthreads();

  for (int it = 0; it < 32; ++it) {
    const int cur = it & 1;
    if (it < 31) {                         // prefetch next K-tile into other buffer
      const int kt = (it + 1) * BK;
      unsigned short* db = (unsigned short*)lds + (cur ^ 1) * 8192;
      GLL(Ag + kt,          db + wave*1024);
      GLL(Ag + kt + 16*D_,  db + wave*1024 + 512);
      GLL(Bg + kt,          db + 4096 + wave*1024);
      GLL(Bg + kt + 16*D_,  db + 4096 + wave*1024 + 512);
    }
    const unsigned short* Ab = (const unsigned short*)lds + cur * 8192;
    const unsigned short* Bb = Ab + 4096;

    bf16x8 af[4], bf0[2], bf1[2];
    #pragma unroll
    for (int i = 0; i < 4; ++i)
      af[i] = *(const bf16x8*)&Ab[(wmblk + i)*512 + lane*8];
    #pragma unroll
    for (int j = 0; j < 2; ++j) {
      bf0[j] = *(const bf16x8*)&Bb[(wnblk + j)*512 + lane*8];
      bf1[j] = *(const bf16x8*)&Bb[(4 + wnblk + j)*512 + lane*8];
    }
    #pragma unroll
    for (int i = 0; i < 4; ++i)
      #pragma unroll
      for (int j = 0; j < 2; ++j) {
        acc[i][j][0] = __builtin_amdgcn_mfma_f32_16x16x32_bf16(af[i], bf0[j], acc[i][j][0], 0, 0, 0);
        acc[i][j][1] = __builtin_amdgcn_mfma_f32_16x16x32_bf16(af[i], bf1[j], acc[i][j][1], 0, 0, 0);
      }
    __syncthreads();   // vmcnt(0) drain: prefetch had the compute phase to land
  }

  // C/D layout: row = q*4 + reg, col = l16
  const int mbase = by*BM + (wave>>1)*64 + q*4;
  const int nbase = bx*64 + (wave&1)*32 + l16;
  #pragma unroll
  for (int j = 0; j < 2; ++j) {
    const int n = nbase + j*16;
    const float ba = b_alpha[n];
    const float bb = b_beta[n];
    #pragma unroll
    for (int i = 0; i < 4; ++i)
      #pragma unroll
      for (int r = 0; r < 4; ++r) {
        const int m = mbase + i*16 + r;
        const size_t idx = (size_t)m*D_ + n;
        float al = sigmoidf_(acc[i][j][0][r] + ba);
        float be = siluf_(acc[i][j][1][r] + bb);
        float vv = v[idx];
        float ws = sqrtf(fmaxf(1.f - al*al, 1e-6f));
        alphas[idx] = al;
        x[idx]      = vv * be * ws;
        v_out[idx]  = vv;
      }
  }
}

// Single-weight GEMM (ctx projection), same pipeline + swizzle.
template<typename Epi>
__global__ __launch_bounds__(256) void gemm128(
    const unsigned short* __restrict__ A, const unsigned short* __restrict__ Bt,
    Epi epi) {
  __shared__ unsigned short lds[2*8192];   // 32 KB double-buffered
  const int tid  = threadIdx.x;
  const int wave = tid >> 6;
  const int lane = tid & 63;
  const int q    = lane >> 4;
  const int l16  = lane & 15;
  const int wmblk = (wave >> 1) * 4;
  const int wnblk = (wave & 1) * 4;

  const int sr = lane & 15;
  const int sk = (lane >> 4) * 8;
  const unsigned short* Ag = A  + ((size_t)blockIdx.y*BM + wave*32 + sr) * D_ + sk;
  const unsigned short* Bg = Bt + ((size_t)blockIdx.x*BN + wave*32 + sr) * D_ + sk;

  f4 acc[4][4] = {};

  GLL(Ag,          lds + wave*1024);
  GLL(Ag + 16*D_,  lds + wave*1024 + 512);
  GLL(Bg,          lds + 4096 + wave*1024);
  GLL(Bg + 16*D_,  lds + 4096 + wave*1024 + 512);
  __syncthreads();

  for (int it = 0; it < 32; ++it) {
    const int cur = it & 1;
    if (it < 31) {
      const int kt = (it + 1) * BK;
      unsigned short* db = (unsigned short*)lds + (cur ^ 1) * 8192;
      GLL(Ag + kt,          db + wave*1024);
      GLL(Ag + kt + 16*D_,  db + wave*1024 + 512);
      GLL(Bg + kt,          db + 4096 + wave*1024);
      GLL(Bg + kt + 16*D_,  db + 4096 + wave*1024 + 512);
    }
    const unsigned short* Ab = (const unsigned short*)lds + cur * 8192;
    const unsigned short* Bb = Ab + 4096;

    bf16x8 af[4], bfr[4];
    #pragma unroll
    for (int i = 0; i < 4; ++i)
      af[i] = *(const bf16x8*)&Ab[(wmblk + i)*512 + lane*8];
    #pragma unroll
    for (int j = 0; j < 4; ++j)
      bfr[j] = *(const bf16x8*)&Bb[(wnblk + j)*512 + lane*8];
    #pragma unroll
    for (int i = 0; i < 4; ++i)
      #pragma unroll
      for (int j = 0; j < 4; ++j)
        acc[i][j] = __builtin_amdgcn_mfma_f32_16x16x32_bf16(af[i], bfr[j], acc[i][j], 0, 0, 0);
    __syncthreads();
  }

  const int mbase = blockIdx.y*BM + (wave>>1)*64 + q*4;
  const int nbase = blockIdx.x*BN + (wave&1)*64 + l16;
  #pragma unroll
  for (int i = 0; i < 4; ++i)
    #pragma unroll
    for (int j = 0; j < 4; ++j)
      #pragma unroll
      for (int r = 0; r < 4; ++r)
        epi(mbase + i*16 + r, nbase + j*16, acc[i][j][r]);
}

struct EpiCtx {
  const float* b_ctx; const float* ctx_in; float* ctx_out;
  __device__ void operator()(int m, int n, float c) const {
    size_t idx = (size_t)m*D_ + n;
    ctx_out[idx] = ctx_in[idx] + siluf_(c + b_ctx[n]);
  }
};

// ---------------- chunked linear recurrence --------------------------------
// pass1: per-chunk summaries (A_prod, h_end)
__global__ __launch_bounds__(256) void scan_pass1(
    const float* __restrict__ x, const float* __restrict__ a,
    float* __restrict__ sumA, float* __restrict__ sumH) {
  const int c = blockIdx.x, b = blockIdx.y;
  const int t4 = threadIdx.x;
  const f4* xp = (const f4*)(x + ((size_t)b*L_ + (size_t)c*LC) * D_) + t4;
  const f4* ap = (const f4*)(a + ((size_t)b*L_ + (size_t)c*LC) * D_) + t4;
  f4 h = {0.f,0.f,0.f,0.f};
  f4 A = {1.f,1.f,1.f,1.f};
  #pragma unroll 4
  for (int t = 0; t < LC; ++t) {
    f4 av = ap[t*(D_/4)];
    f4 xv = xp[t*(D_/4)];
    h = av*h + xv;
    A = av*A;
  }
  size_t o = ((size_t)c*B_ + b) * (D_/4) + t4;
  ((f4*)sumA)[o] = A;
  ((f4*)sumH)[o] = h;
}

// sequential combine over chunks -> carry-in per chunk
__global__ __launch_bounds__(256) void scan_combine(
    const float* __restrict__ sumA, const float* __restrict__ sumH,
    float* __restrict__ carry) {
  const int id = blockIdx.x*256 + threadIdx.x;    // 0..4095 = (b,d)
  const int b = id >> 10, d = id & (D_-1);
  float H = 0.f;
  for (int c = 0; c < NC; ++c) {
    size_t idx = ((size_t)c*B_ + b)*D_ + d;
    carry[idx] = H;
    H = sumA[idx]*H + sumH[idx];
  }
}

// pass2: recompute with carry-in; fuse out_out = out + h; emit bf16 copy of h
__global__ __launch_bounds__(256) void scan_pass2(
    const float* __restrict__ x, const float* __restrict__ a,
    const float* __restrict__ carry, const float* __restrict__ out_in,
    float* __restrict__ out_out, unsigned short* __restrict__ fbf) {
  const int c = blockIdx.x, b = blockIdx.y;
  const int t4 = threadIdx.x;
  const size_t base4 = (((size_t)b*L_ + (size_t)c*LC) * D_) / 4;
  f4 h = ((const f4*)carry)[((size_t)c*B_ + b)*(D_/4) + t4];
  #pragma unroll 4
  for (int t = 0; t < LC; ++t) {
    size_t o4 = base4 + (size_t)t*(D_/4) + t4;
    f4 av = ((const f4*)a)[o4];
    f4 xv = ((const f4*)x)[o4];
    h = av*h + xv;
    f4 ov = ((const f4*)out_in)[o4];
    ((f4*)out_out)[o4] = ov + h;
    ushort4 hb; hb.x = f2bf(h.x); hb.y = f2bf(h.y); hb.z = f2bf(h.z); hb.w = f2bf(h.w);
    *(ushort4*)&fbf[o4*4] = hb;
  }
}

// ---------------- launch ---------------------------------------------------
extern "C" void kernel_launch(void* const* d_in, const int* in_sizes, int n_in,
                              void* d_out, int out_size, void* d_ws, size_t ws_size,
                              hipStream_t stream) {
  (void)in_sizes; (void)n_in; (void)out_size; (void)ws_size;
  const float* v       = (const float*)d_in[0];
  const float* ctx     = (const float*)d_in[1];
  const float* outp    = (const float*)d_in[2];
  const float* alog    = (const float*)d_in[3];
  const float* g_rms   = (const float*)d_in[4];
  const float* W_alpha = (const float*)d_in[5];
  const float* b_alpha = (const float*)d_in[6];
  const float* W_beta  = (const float*)d_in[7];
  const float* b_beta  = (const float*)d_in[8];
  const float* W_ctx   = (const float*)d_in[9];
  const float* b_ctx   = (const float*)d_in[10];

  float* S0 = (float*)d_out;   // final: v        (written by gemm_ab epilogue)
  float* S1 = S0 + SLOT;       // final: ctx_out  (holds x until gemm_ctx)
  float* S2 = S1 + SLOT;       // final: out_out  (holds ctx_norm bf16 early)
  float* S3 = S2 + SLOT;       // final: alpha_logits (holds alphas early)

  // workspace layout (41 MB total)
  char* w = (char*)d_ws;
  unsigned short* Wab  = (unsigned short*)w;                   // [2048,1024] bf16, 4 MB
  unsigned short* Wct  = (unsigned short*)(w + (size_t)4*1024*1024);   // 2 MB
  unsigned short* fbf  = (unsigned short*)(w + (size_t)6*1024*1024);   // fetched bf16, 32 MB
  float* sumA  = (float*)(w + (size_t)38*1024*1024);           // 1 MB
  float* sumH  = (float*)(w + (size_t)39*1024*1024);           // 1 MB
  float* carry = (float*)(w + (size_t)40*1024*1024);           // 1 MB

  unsigned short* ctxn = (unsigned short*)S2;  // ctx_norm bf16 staged in S2
  float* alphas = S3;
  float* xbuf   = S1;

  transpose_cvt<<<dim3(32,32,3), dim3(32,8), 0, stream>>>(W_alpha, W_beta, W_ctx, Wab, Wct);
  rmsnorm_bf16<<<dim3(M_), dim3(256), 0, stream>>>(ctx, g_rms, ctxn);
  gemm_ab<<<dim3(D_/64, M_/BM), dim3(256), 0, stream>>>(ctxn, Wab,
      b_alpha, b_beta, v, alphas, xbuf, S0);
  scan_pass1<<<dim3(NC, B_), dim3(256), 0, stream>>>(xbuf, alphas, sumA, sumH);
  scan_combine<<<dim3(16), dim3(256), 0, stream>>>(sumA, sumH, carry);
  scan_pass2<<<dim3(NC, B_), dim3(256), 0, stream>>>(xbuf, alphas, carry, outp, S2, fbf);
  gemm128<<<dim3(D_/BN, M_/BM), dim3(256), 0, stream>>>(fbf, Wct,
      EpiCtx{b_ctx, ctx, S1});
  hipMemcpyAsync(S3, alog, SLOT*sizeof(float), hipMemcpyDeviceToDevice, stream);
}

// Round 3
// 798.157 us; speedup vs baseline: 1.0343x; 1.0343x over previous
//
#include <hip/hip_runtime.h>

// Problem constants (B=4, L=4096, D=1024 fixed by the reference setup)
#define B_ 4
#define L_ 4096
#define D_ 1024
#define M_ (B_*L_)              // 16384 rows
#define LC 64                   // scan chunk length
#define NC (L_/LC)              // 64 chunks
#define SLOT ((size_t)M_*D_)    // elements per output slot (16,777,216)

typedef __attribute__((ext_vector_type(4))) float f4;
typedef __bf16 bf16x8 __attribute__((ext_vector_type(8)));

__device__ __forceinline__ unsigned short f2bf(float f) {
  unsigned int u = __float_as_uint(f);
  u += 0x7FFFu + ((u >> 16) & 1u);         // round-to-nearest-even
  return (unsigned short)(u >> 16);
}
__device__ __forceinline__ float sigmoidf_(float x) { return 1.f / (1.f + __expf(-x)); }
__device__ __forceinline__ float siluf_(float x)    { return x / (1.f + __expf(-x)); }

#define GLL(src, dst) __builtin_amdgcn_global_load_lds( \
    (const __attribute__((address_space(1))) void*)(src), \
    (__attribute__((address_space(3))) void*)(dst), 16, 0, 0)

// counted-vmcnt pipeline primitives (T4): raw barrier, manual waits.
#define VMWAIT8 asm volatile("s_waitcnt vmcnt(8)" ::: "memory")
#define VMWAIT0 asm volatile("s_waitcnt vmcnt(0)" ::: "memory")
#define LGWAIT0 asm volatile("s_waitcnt lgkmcnt(0)" ::: "memory")
#define BAR()   __builtin_amdgcn_s_barrier()

// ---------------- weight transpose + fp32->bf16 convert -------------------
__global__ __launch_bounds__(256) void transpose_cvt(
    const float* __restrict__ Wa, const float* __restrict__ Wb,
    const float* __restrict__ Wc,
    unsigned short* __restrict__ Wab, unsigned short* __restrict__ Wct) {
  __shared__ float tile[32][33];
  const float* src = (blockIdx.z == 0) ? Wa : (blockIdx.z == 1 ? Wb : Wc);
  unsigned short* dst = (blockIdx.z == 2) ? Wct
                        : (Wab + (blockIdx.z == 1 ? (size_t)D_*D_ : 0));
  int n = blockIdx.x*32 + threadIdx.x;     // source col
  int k0 = blockIdx.y*32;                  // source row base
  for (int i = threadIdx.y; i < 32; i += 8)
    tile[i][threadIdx.x] = src[(size_t)(k0+i)*D_ + n];
  __syncthreads();
  int k = k0 + threadIdx.x;
  int n0 = blockIdx.x*32;
  for (int i = threadIdx.y; i < 32; i += 8)
    dst[(size_t)(n0+i)*D_ + k] = f2bf(tile[threadIdx.x][i]);
}

// ---------------- RMSNorm -> bf16 ----------------------------------------
__global__ __launch_bounds__(256) void rmsnorm_bf16(
    const float* __restrict__ ctx, const float* __restrict__ g,
    unsigned short* __restrict__ out) {
  const size_t row = blockIdx.x;
  const int t = threadIdx.x;
  f4 xv = ((const f4*)(ctx + row*D_))[t];
  float ss = xv.x*xv.x + xv.y*xv.y + xv.z*xv.z + xv.w*xv.w;
  #pragma unroll
  for (int o = 32; o > 0; o >>= 1) ss += __shfl_down(ss, o);
  __shared__ float red[4];
  if ((t & 63) == 0) red[t >> 6] = ss;
  __syncthreads();
  float tot = red[0] + red[1] + red[2] + red[3];
  float sc = rsqrtf(tot * (1.f/(float)D_) + 1e-6f);
  f4 gv = ((const f4*)g)[t];
  f4 y = xv * sc * gv;
  ushort4 o4; o4.x = f2bf(y.x); o4.y = f2bf(y.y); o4.z = f2bf(y.z); o4.w = f2bf(y.w);
  ((ushort4*)out)[row*(D_/4) + t] = o4;
}

// ---------------- bf16 MFMA GEMM kernels ----------------------------------
// Structure (both GEMMs):
//  * BK=64 (2x compute per sync point), 16 K-iters, 64KB LDS double-buffer
//    -> 2 blocks/CU.
//  * Counted-vmcnt 2-phase pipeline: STAGE(next) -> vmcnt(8) [prev tile's
//    8 loads done, this iter's 8 stay in flight] -> BAR1 -> ds_read all
//    frags -> lgkmcnt(0) -> BAR2 [safe to overwrite] -> 32 MFMA.
//    Tail iter drains vmcnt(0). Never __syncthreads in the loop.
//  * LDS chunk layout (1KB per (blk16,khalf) chunk): lane-slot l holds
//    row=(l&15), k=khalf*32+(l>>4)*8 -- fragment reads are base+lane*16,
//    dense, bank-conflict-free (verified round 2: conflicts 8.4M->0).
//  * XCD-grouped bid remap so blocks sharing an A row-panel run
//    consecutively on one XCD (A panel stays in that L2).

// Fused dual-weight GEMM: 128 rows x (64 cols of Wa + 64 cols of Wb).
__global__ __launch_bounds__(256) void gemm_ab(
    const unsigned short* __restrict__ A, const unsigned short* __restrict__ Wab,
    const float* __restrict__ b_alpha, const float* __restrict__ b_beta,
    const float* __restrict__ v,
    float* __restrict__ alphas, float* __restrict__ x, float* __restrict__ v_out) {
  __shared__ unsigned short lds[2*16384];   // 64 KB: 2 x (A 16KB | B 16KB)
  const int tid  = threadIdx.x;
  const int wave = tid >> 6;
  const int lane = tid & 63;
  const int q    = lane >> 4;
  const int l16  = lane & 15;

  // 2048 blocks = 8 xcd * 16 by * 16 bx (bijective)
  const int bid  = blockIdx.x;
  const int xcd  = bid & 7;
  const int slot = bid >> 3;
  const int by   = xcd*16 + (slot >> 4);
  const int bx   = slot & 15;

  const int sr = lane & 15;
  const int sk = (lane >> 4) * 8;
  const bool isA = wave < 2;
  // waves 0,1 stage A rows [wave*64, wave*64+64); waves 2,3 stage weight
  // (wave&1)'s 64 B-rows. 8 GLL/wave/iter, each 1KB chunk (blk=g>>1, kh=g&1).
  const unsigned short* gsrc = isA
    ? A   + ((size_t)(by*128 + wave*64        + sr))*D_ + sk
    : Wab + ((size_t)((wave&1)*D_ + bx*64 + sr))*D_ + sk;
  const int wdst = (isA ? 0 : 8192) + (isA ? wave : (wave&1))*4096;

  const int aoff = (wave>>1)*4096;          // A frag chunk base (shorts)
  const int boff = 8192 + (wave&1)*2048;    // B frag base within weight-0 region

  f4 acc[4][2][2] = {};                     // [m-frag][n-frag][weight]

#define STAGE_AB(bufs, kts) do { \
    _Pragma("unroll") \
    for (int g = 0; g < 8; ++g) \
      GLL(gsrc + (kts) + (g>>1)*16*D_ + (g&1)*32, (bufs) + wdst + g*512); \
  } while (0)

  STAGE_AB(lds, 0);
  for (int it = 0; it < 16; ++it) {
    unsigned short* cb = lds + (it & 1)*16384;
    if (it < 15) {
      STAGE_AB(lds + ((it & 1)^1)*16384, (it+1)*64);
      VMWAIT8;
    } else {
      VMWAIT0;
    }
    BAR();                                  // buf[cur] landed (all waves)
    bf16x8 af[2][4], b0[2][2], b1[2][2];
    #pragma unroll
    for (int kh = 0; kh < 2; ++kh) {
      #pragma unroll
      for (int i = 0; i < 4; ++i)
        af[kh][i] = *(const bf16x8*)&cb[aoff + i*1024 + kh*512 + lane*8];
      #pragma unroll
      for (int j = 0; j < 2; ++j) {
        b0[kh][j] = *(const bf16x8*)&cb[boff + j*1024 + kh*512 + lane*8];
        b1[kh][j] = *(const bf16x8*)&cb[boff + 4096 + j*1024 + kh*512 + lane*8];
      }
    }
    LGWAIT0;
    BAR();                                  // reads in regs; next STAGE may overwrite
    #pragma unroll
    for (int kh = 0; kh < 2; ++kh)
      #pragma unroll
      for (int i = 0; i < 4; ++i)
        #pragma unroll
        for (int j = 0; j < 2; ++j) {
          acc[i][j][0] = __builtin_amdgcn_mfma_f32_16x16x32_bf16(af[kh][i], b0[kh][j], acc[i][j][0], 0, 0, 0);
          acc[i][j][1] = __builtin_amdgcn_mfma_f32_16x16x32_bf16(af[kh][i], b1[kh][j], acc[i][j][1], 0, 0, 0);
        }
  }
#undef STAGE_AB

  // C/D layout: row = q*4 + reg, col = l16 (HW-verified)
  const int mbase = by*128 + (wave>>1)*64 + q*4;
  const int nbase = bx*64 + (wave&1)*32 + l16;
  #pragma unroll
  for (int j = 0; j < 2; ++j) {
    const int n = nbase + j*16;
    const float ba = b_alpha[n];
    const float bb = b_beta[n];
    #pragma unroll
    for (int i = 0; i < 4; ++i)
      #pragma unroll
      for (int r = 0; r < 4; ++r) {
        const int m = mbase + i*16 + r;
        const size_t idx = (size_t)m*D_ + n;
        float al = sigmoidf_(acc[i][j][0][r] + ba);
        float be = siluf_(acc[i][j][1][r] + bb);
        float vv = v[idx];
        float ws = sqrtf(fmaxf(1.f - al*al, 1e-6f));
        alphas[idx] = al;
        x[idx]      = vv * be * ws;
        v_out[idx]  = vv;
      }
  }
}

// Single-weight GEMM (ctx projection): 128x128 tile, same pipeline.
template<typename Epi>
__global__ __launch_bounds__(256) void gemm128(
    const unsigned short* __restrict__ A, const unsigned short* __restrict__ Bt,
    Epi epi) {
  __shared__ unsigned short lds[2*16384];   // 64 KB
  const int tid  = threadIdx.x;
  const int wave = tid >> 6;
  const int lane = tid & 63;
  const int q    = lane >> 4;
  const int l16  = lane & 15;

  // 1024 blocks = 8 xcd * 16 by * 8 bx (bijective)
  const int bid  = blockIdx.x;
  const int xcd  = bid & 7;
  const int slot = bid >> 3;
  const int by   = xcd*16 + (slot >> 3);
  const int bx   = slot & 7;

  const int sr = lane & 15;
  const int sk = (lane >> 4) * 8;
  const bool isA = wave < 2;
  const unsigned short* gsrc = isA
    ? A  + ((size_t)(by*128 + wave*64          + sr))*D_ + sk
    : Bt + ((size_t)(bx*128 + (wave&1)*64 + sr))*D_ + sk;
  const int wdst = (isA ? 0 : 8192) + (isA ? wave : (wave&1))*4096;

  const int aoff = (wave>>1)*4096;
  const int boff = 8192 + (wave&1)*4096;

  f4 acc[4][4] = {};

#define STAGE_C(bufs, kts) do { \
    _Pragma("unroll") \
    for (int g = 0; g < 8; ++g) \
      GLL(gsrc + (kts) + (g>>1)*16*D_ + (g&1)*32, (bufs) + wdst + g*512); \
  } while (0)

  STAGE_C(lds, 0);
  for (int it = 0; it < 16; ++it) {
    unsigned short* cb = lds + (it & 1)*16384;
    if (it < 15) {
      STAGE_C(lds + ((it & 1)^1)*16384, (it+1)*64);
      VMWAIT8;
    } else {
      VMWAIT0;
    }
    BAR();
    bf16x8 af[2][4], bfr[2][4];
    #pragma unroll
    for (int kh = 0; kh < 2; ++kh) {
      #pragma unroll
      for (int i = 0; i < 4; ++i)
        af[kh][i] = *(const bf16x8*)&cb[aoff + i*1024 + kh*512 + lane*8];
      #pragma unroll
      for (int j = 0; j < 4; ++j)
        bfr[kh][j] = *(const bf16x8*)&cb[boff + j*1024 + kh*512 + lane*8];
    }
    LGWAIT0;
    BAR();
    #pragma unroll
    for (int kh = 0; kh < 2; ++kh)
      #pragma unroll
      for (int i = 0; i < 4; ++i)
        #pragma unroll
        for (int j = 0; j < 4; ++j)
          acc[i][j] = __builtin_amdgcn_mfma_f32_16x16x32_bf16(af[kh][i], bfr[kh][j], acc[i][j], 0, 0, 0);
  }
#undef STAGE_C

  const int mbase = by*128 + (wave>>1)*64 + q*4;
  const int nbase = bx*128 + (wave&1)*64 + l16;
  #pragma unroll
  for (int i = 0; i < 4; ++i)
    #pragma unroll
    for (int j = 0; j < 4; ++j)
      #pragma unroll
      for (int r = 0; r < 4; ++r)
        epi(mbase + i*16 + r, nbase + j*16, acc[i][j][r]);
}

struct EpiCtx {
  const float* b_ctx; const float* ctx_in; float* ctx_out;
  __device__ void operator()(int m, int n, float c) const {
    size_t idx = (size_t)m*D_ + n;
    ctx_out[idx] = ctx_in[idx] + siluf_(c + b_ctx[n]);
  }
};

// ---------------- chunked linear recurrence --------------------------------
__global__ __launch_bounds__(256) void scan_pass1(
    const float* __restrict__ x, const float* __restrict__ a,
    float* __restrict__ sumA, float* __restrict__ sumH) {
  const int c = blockIdx.x, b = blockIdx.y;
  const int t4 = threadIdx.x;
  const f4* xp = (const f4*)(x + ((size_t)b*L_ + (size_t)c*LC) * D_) + t4;
  const f4* ap = (const f4*)(a + ((size_t)b*L_ + (size_t)c*LC) * D_) + t4;
  f4 h = {0.f,0.f,0.f,0.f};
  f4 A = {1.f,1.f,1.f,1.f};
  #pragma unroll 4
  for (int t = 0; t < LC; ++t) {
    f4 av = ap[t*(D_/4)];
    f4 xv = xp[t*(D_/4)];
    h = av*h + xv;
    A = av*A;
  }
  size_t o = ((size_t)c*B_ + b) * (D_/4) + t4;
  ((f4*)sumA)[o] = A;
  ((f4*)sumH)[o] = h;
}

__global__ __launch_bounds__(256) void scan_combine(
    const float* __restrict__ sumA, const float* __restrict__ sumH,
    float* __restrict__ carry) {
  const int id = blockIdx.x*256 + threadIdx.x;    // 0..4095 = (b,d)
  const int b = id >> 10, d = id & (D_-1);
  float H = 0.f;
  for (int c = 0; c < NC; ++c) {
    size_t idx = ((size_t)c*B_ + b)*D_ + d;
    carry[idx] = H;
    H = sumA[idx]*H + sumH[idx];
  }
}

__global__ __launch_bounds__(256) void scan_pass2(
    const float* __restrict__ x, const float* __restrict__ a,
    const float* __restrict__ carry, const float* __restrict__ out_in,
    float* __restrict__ out_out, unsigned short* __restrict__ fbf) {
  const int c = blockIdx.x, b = blockIdx.y;
  const int t4 = threadIdx.x;
  const size_t base4 = (((size_t)b*L_ + (size_t)c*LC) * D_) / 4;
  f4 h = ((const f4*)carry)[((size_t)c*B_ + b)*(D_/4) + t4];
  #pragma unroll 4
  for (int t = 0; t < LC; ++t) {
    size_t o4 = base4 + (size_t)t*(D_/4) + t4;
    f4 av = ((const f4*)a)[o4];
    f4 xv = ((const f4*)x)[o4];
    h = av*h + xv;
    f4 ov = ((const f4*)out_in)[o4];
    ((f4*)out_out)[o4] = ov + h;
    ushort4 hb; hb.x = f2bf(h.x); hb.y = f2bf(h.y); hb.z = f2bf(h.z); hb.w = f2bf(h.w);
    *(ushort4*)&fbf[o4*4] = hb;
  }
}

// ---------------- launch ---------------------------------------------------
extern "C" void kernel_launch(void* const* d_in, const int* in_sizes, int n_in,
                              void* d_out, int out_size, void* d_ws, size_t ws_size,
                              hipStream_t stream) {
  (void)in_sizes; (void)n_in; (void)out_size; (void)ws_size;
  const float* v       = (const float*)d_in[0];
  const float* ctx     = (const float*)d_in[1];
  const float* outp    = (const float*)d_in[2];
  const float* alog    = (const float*)d_in[3];
  const float* g_rms   = (const float*)d_in[4];
  const float* W_alpha = (const float*)d_in[5];
  const float* b_alpha = (const float*)d_in[6];
  const float* W_beta  = (const float*)d_in[7];
  const float* b_beta  = (const float*)d_in[8];
  const float* W_ctx   = (const float*)d_in[9];
  const float* b_ctx   = (const float*)d_in[10];

  float* S0 = (float*)d_out;   // final: v        (written by gemm_ab epilogue)
  float* S1 = S0 + SLOT;       // final: ctx_out  (holds x until gemm_ctx)
  float* S2 = S1 + SLOT;       // final: out_out  (holds ctx_norm bf16 early)
  float* S3 = S2 + SLOT;       // final: alpha_logits (holds alphas early)

  // workspace layout (41 MB total)
  char* w = (char*)d_ws;
  unsigned short* Wab  = (unsigned short*)w;                   // [2048,1024] bf16, 4 MB
  unsigned short* Wct  = (unsigned short*)(w + (size_t)4*1024*1024);   // 2 MB
  unsigned short* fbf  = (unsigned short*)(w + (size_t)6*1024*1024);   // fetched bf16, 32 MB
  float* sumA  = (float*)(w + (size_t)38*1024*1024);           // 1 MB
  float* sumH  = (float*)(w + (size_t)39*1024*1024);           // 1 MB
  float* carry = (float*)(w + (size_t)40*1024*1024);           // 1 MB

  unsigned short* ctxn = (unsigned short*)S2;  // ctx_norm bf16 staged in S2
  float* alphas = S3;
  float* xbuf   = S1;

  transpose_cvt<<<dim3(32,32,3), dim3(32,8), 0, stream>>>(W_alpha, W_beta, W_ctx, Wab, Wct);
  rmsnorm_bf16<<<dim3(M_), dim3(256), 0, stream>>>(ctx, g_rms, ctxn);
  gemm_ab<<<dim3(2048), dim3(256), 0, stream>>>(ctxn, Wab,
      b_alpha, b_beta, v, alphas, xbuf, S0);
  scan_pass1<<<dim3(NC, B_), dim3(256), 0, stream>>>(xbuf, alphas, sumA, sumH);
  scan_combine<<<dim3(16), dim3(256), 0, stream>>>(sumA, sumH, carry);
  scan_pass2<<<dim3(NC, B_), dim3(256), 0, stream>>>(xbuf, alphas, carry, outp, S2, fbf);
  gemm128<<<dim3(1024), dim3(256), 0, stream>>>(fbf, Wct,
      EpiCtx{b_ctx, ctx, S1});
  hipMemcpyAsync(S3, alog, SLOT*sizeof(float), hipMemcpyDeviceToDevice, stream);
}